// Round 2
// baseline (489.175 us; speedup 1.0000x reference)
//
#include <hip/hip_runtime.h>
#include <hip/hip_bf16.h>

typedef float f32x4 __attribute__((ext_vector_type(4)));
typedef __bf16 bf16x8 __attribute__((ext_vector_type(8)));
typedef __bf16 bf16x4 __attribute__((ext_vector_type(4)));

#define N_NODES 8192
#define IN_F    128
#define HID_F   256
#define OUT_F   64
#define SPLIT1  8
#define SPLIT2  16

// async global->LDS DMA, 16B per lane. LDS dst = wave-uniform base + lane*16.
// Generic LDS pointer's low 32 bits are the LDS byte offset on amdgcn.
__device__ __forceinline__ void dma16(const void* g, void* l) {
  __builtin_amdgcn_global_load_lds(
      (const __attribute__((address_space(1))) void*)g,
      (__attribute__((address_space(3))) void*)(uint32_t)(uintptr_t)l, 16, 0, 0);
}

// counted vmcnt wait — immediate must be a literal in the instruction text.
template <int K> __device__ __forceinline__ void wait_vmcnt() {
  if constexpr (K == 0)       asm volatile("s_waitcnt vmcnt(0)" ::: "memory");
  else if constexpr (K == 4)  asm volatile("s_waitcnt vmcnt(4)" ::: "memory");
  else if constexpr (K == 5)  asm volatile("s_waitcnt vmcnt(5)" ::: "memory");
  else if constexpr (K == 8)  asm volatile("s_waitcnt vmcnt(8)" ::: "memory");
  else if constexpr (K == 10) asm volatile("s_waitcnt vmcnt(10)" ::: "memory");
  else if constexpr (K == 12) asm volatile("s_waitcnt vmcnt(12)" ::: "memory");
  else if constexpr (K == 15) asm volatile("s_waitcnt vmcnt(15)" ::: "memory");
  else static_assert(K == 0, "unsupported vmcnt literal");
}

// ---- Kernel 1: deg rowsum + fp32->bf16 convert of adj into adjb ----
__global__ __launch_bounds__(256) void k_degcvt(const float* __restrict__ adj,
                                                __bf16* __restrict__ adjb,
                                                float* __restrict__ d) {
  const int row = blockIdx.x;
  const int t = threadIdx.x;
  const f32x4* p = (const f32x4*)(adj + (size_t)row * N_NODES);
  bf16x4* q = (bf16x4*)(adjb + (size_t)row * N_NODES);
  float s = 0.f;
#pragma unroll
  for (int i = 0; i < N_NODES / (256 * 4); ++i) {
    f32x4 v = p[i * 256 + t];
    s += v[0] + v[1] + v[2] + v[3];
    bf16x4 o = {(__bf16)v[0], (__bf16)v[1], (__bf16)v[2], (__bf16)v[3]};
    q[i * 256 + t] = o;
  }
#pragma unroll
  for (int off = 32; off > 0; off >>= 1) s += __shfl_down(s, off);
  __shared__ float red[4];
  if ((t & 63) == 0) red[t >> 6] = s;
  __syncthreads();
  if (t == 0) d[row] = rsqrtf(red[0] + red[1] + red[2] + red[3] + 1e-8f);
}

// ---- Kernel 2: Bt1[c][j] = bf16(d[j] * x[j][c]) ----
__global__ __launch_bounds__(256) void k_bt1(const float* __restrict__ x,
                                             const float* __restrict__ d,
                                             __bf16* __restrict__ Bt1) {
  __shared__ __bf16 tile[IN_F][64 + 2];
  const int t = threadIdx.x;
  const int j0 = blockIdx.x * 64;
#pragma unroll
  for (int rep = 0; rep < 32; ++rep) {
    int e = rep * 256 + t;
    int j = e >> 7, c = e & 127;
    tile[c][j] = (__bf16)(x[(size_t)(j0 + j) * IN_F + c] * d[j0 + j]);
  }
  __syncthreads();
#pragma unroll
  for (int rep = 0; rep < 32; ++rep) {
    int e = rep * 256 + t;
    int c = e >> 6, jj = e & 63;
    Bt1[(size_t)c * N_NODES + j0 + jj] = tile[c][jj];
  }
}

__device__ inline bf16x8 load_frag(const float* p) {
  f32x4 a = *(const f32x4*)p;
  f32x4 b = *(const f32x4*)(p + 4);
  bf16x8 o = {(__bf16)a[0], (__bf16)a[1], (__bf16)a[2], (__bf16)a[3],
              (__bf16)b[0], (__bf16)b[1], (__bf16)b[2], (__bf16)b[3]};
  return o;
}

// ---- one pipelined K-step of the DMA-staged GEMM ----
// 4-deep circular LDS pipeline, counted vmcnt (stages stay in flight across
// barriers). Buffer (t&3) is only overwritten by stage t+4, whose issue is
// fenced behind this iteration's trailing lgkmcnt(0)+s_barrier.
template <int WGM, int WGN, int KC, int KWAIT>
__device__ __forceinline__ void g_iter(char* sm, int t, int w,
                                       const __bf16* (&a_src)[WGM],
                                       const __bf16* (&b_src)[WGN],
                                       const int (&offA)[4],
                                       const int (&offB)[4],
                                       f32x4 (&acc)[4][4]) {
  constexpr int BM = WGM * 64, BN = WGN * 64;
  constexpr int ABYTES = BM * 64;
  constexpr int STAGE = (BM + BN) * 64;
  constexpr int NIT = KC / 32;

  if (t + 3 < NIT) {  // issue stage t+3 into buf[(t+3)&3]
    char* nb = sm + ((t + 3) & 3) * STAGE;
#pragma unroll
    for (int kk = 0; kk < WGM; ++kk) {
      dma16(a_src[kk], nb + kk * 4096 + (w << 10));
      a_src[kk] += 32;
    }
#pragma unroll
    for (int kk = 0; kk < WGN; ++kk) {
      dma16(b_src[kk], nb + ABYTES + kk * 4096 + (w << 10));
      b_src[kk] += 32;
    }
  }
  // pin DMA issues above the counted wait (count correctness depends on it)
  __builtin_amdgcn_sched_barrier(0);
  wait_vmcnt<KWAIT>();                       // stage t complete (this wave)
  asm volatile("s_barrier" ::: "memory");    // stage t complete (all waves)
  __builtin_amdgcn_sched_barrier(0);         // keep ds_reads below barrier

  const char* cb = sm + (t & 3) * STAGE;
  bf16x8 af[4], bfr[4];
#pragma unroll
  for (int tm = 0; tm < 4; ++tm) af[tm] = *(const bf16x8*)(cb + offA[tm]);
#pragma unroll
  for (int ct = 0; ct < 4; ++ct) bfr[ct] = *(const bf16x8*)(cb + offB[ct]);
#pragma unroll
  for (int tm = 0; tm < 4; ++tm)
#pragma unroll
    for (int ct = 0; ct < 4; ++ct)
      acc[tm][ct] = __builtin_amdgcn_mfma_f32_16x16x32_bf16(
          af[tm], bfr[ct], acc[tm][ct], 0, 0, 0);

  // reads of buf[t&3] landed before anyone may issue stage t+4 (next iter)
  __builtin_amdgcn_sched_barrier(0);
  asm volatile("s_waitcnt lgkmcnt(0)" ::: "memory");
  asm volatile("s_barrier" ::: "memory");
}

// ---- DMA-staged MFMA GEMM partials: P[s][m][c] = adj_tile @ Bt^T ----
// Block tile: BM x BN (BM=WGM*64, BN=WGN*64), 4 waves in WGM x WGN grid,
// wave tile 64x64 (TM=4,NT=4). K-chunk KC per blockIdx.y. LDS 4-deep circular,
// staged via global_load_lds w/ chunk swizzle c ^= (row>>1)&3 (bank-friendly).
template <int WGM, int WGN, int KC>
__global__ __launch_bounds__(256, 2) void k_gemm_dma(
    const __bf16* __restrict__ A, const __bf16* __restrict__ Bt,
    float* __restrict__ P) {
  constexpr int BM = WGM * 64, BN = WGN * 64;
  constexpr int ANI = BM / 64, BNI = BN / 64;   // staging instrs per thread
  constexpr int ABYTES = BM * 64;               // A region bytes per stage
  constexpr int STAGE = (BM + BN) * 64;         // one stage buffer
  constexpr int NIT = KC / 32;
  constexpr int L = ANI + BNI;                  // vm loads/thread/stage
  static_assert(NIT > 3, "pipeline needs >3 K-steps");

  __shared__ __align__(16) char sm[4 * STAGE];

  const int t = threadIdx.x;
  const int w = t >> 6, lane = t & 63;
  const int r = lane & 15, q = lane >> 4;
  const int wm = (WGN == 1) ? w : (w >> 1);
  const int wn = (WGN == 1) ? 0 : (w & 1);
  const int m0 = blockIdx.x * BM;
  const int ks = blockIdx.y;
  const int k0 = ks * KC;

  // staging source pointers (per-thread): chunk L = kk*256 + t -> row n=L>>2,
  // chunk slot c=L&3, stored swizzled: holds global chunk c ^ ((n>>1)&3).
  const int n_ = t >> 2;
  const int csw = (t & 3) ^ ((t >> 3) & 3);
  const __bf16* a_src[ANI];
  const __bf16* b_src[BNI];
#pragma unroll
  for (int kk = 0; kk < ANI; ++kk)
    a_src[kk] = A + (size_t)(m0 + n_ + 64 * kk) * N_NODES + k0 + csw * 8;
#pragma unroll
  for (int kk = 0; kk < BNI; ++kk)
    b_src[kk] = Bt + (size_t)(n_ + 64 * kk) * N_NODES + k0 + csw * 8;

  // fragment LDS byte offsets (loop-invariant): row*64 + (q^((row>>1)&3))*16
  int offA[4], offB[4];
#pragma unroll
  for (int tm = 0; tm < 4; ++tm) {
    const int row = wm * 64 + tm * 16 + r;
    offA[tm] = row * 64 + ((q ^ ((row >> 1) & 3)) << 4);
  }
#pragma unroll
  for (int ct = 0; ct < 4; ++ct) {
    const int row = wn * 64 + ct * 16 + r;
    offB[ct] = ABYTES + row * 64 + ((q ^ ((row >> 1) & 3)) << 4);
  }

  f32x4 acc[4][4];
#pragma unroll
  for (int tm = 0; tm < 4; ++tm)
#pragma unroll
    for (int ct = 0; ct < 4; ++ct) acc[tm][ct] = (f32x4){0.f, 0.f, 0.f, 0.f};

  // prologue: fill stages 0..2
#pragma unroll
  for (int s = 0; s < 3; ++s) {
    char* sb = sm + s * STAGE;
#pragma unroll
    for (int kk = 0; kk < ANI; ++kk) {
      dma16(a_src[kk], sb + kk * 4096 + (w << 10));
      a_src[kk] += 32;
    }
#pragma unroll
    for (int kk = 0; kk < BNI; ++kk) {
      dma16(b_src[kk], sb + ABYTES + kk * 4096 + (w << 10));
      b_src[kk] += 32;
    }
  }

  for (int it = 0; it < NIT - 3; ++it)
    g_iter<WGM, WGN, KC, 3 * L>(sm, it, w, a_src, b_src, offA, offB, acc);
  g_iter<WGM, WGN, KC, 2 * L>(sm, NIT - 3, w, a_src, b_src, offA, offB, acc);
  g_iter<WGM, WGN, KC, L>(sm, NIT - 2, w, a_src, b_src, offA, offB, acc);
  g_iter<WGM, WGN, KC, 0>(sm, NIT - 1, w, a_src, b_src, offA, offB, acc);

  // epilogue: C/D layout col=lane&15, row=q*4+reg
  float* pout =
      P + ((size_t)ks * N_NODES + m0 + wm * 64 + q * 4) * BN + wn * 64 + r;
#pragma unroll
  for (int tm = 0; tm < 4; ++tm)
#pragma unroll
    for (int ct = 0; ct < 4; ++ct)
#pragma unroll
      for (int i = 0; i < 4; ++i)
        pout[(size_t)(tm * 16 + i) * BN + ct * 16] = acc[tm][ct][i];
}

// ---- reduce P1 + MLP (bf16 MFMA) + build Bt2, 16 nodes per block ----
__global__ __launch_bounds__(256) void k_red_mlp(const float* __restrict__ P1,
                                                 const float* __restrict__ dvec,
                                                 const float* __restrict__ W1,
                                                 const float* __restrict__ b1,
                                                 const float* __restrict__ W2,
                                                 __bf16* __restrict__ Bt2) {
  __shared__ __align__(16) float y[16][IN_F + 4];
  __shared__ __align__(16) __bf16 h[16][HID_F + 8];
  __shared__ __align__(16) float gl[OUT_F][20];
  __shared__ float dl[16];
  const int t = threadIdx.x;
  const int lane = t & 63;
  const int w = t >> 6;
  const int r = lane & 15, q = lane >> 4;
  const int j0 = blockIdx.x * 16;

  if (t < 16) dl[t] = dvec[j0 + t];
  const size_t plane4 = (size_t)N_NODES * IN_F / 4;
  for (int e = t; e < 16 * IN_F / 4; e += 256) {
    const int jj = e >> 5, c4 = e & 31;
    const size_t base = (size_t)(j0 + jj) * (IN_F / 4) + c4;
    f32x4 v = (f32x4){0.f, 0.f, 0.f, 0.f};
#pragma unroll
    for (int s = 0; s < SPLIT1; ++s) v += ((const f32x4*)P1)[base + s * plane4];
    const float dj = dvec[j0 + jj];
    v *= dj;
    *(f32x4*)&y[jj][c4 * 4] = v;
  }
  __syncthreads();

  // h tile: wave w -> hid cols [w*64, w*64+64)
  f32x4 hacc[4];
#pragma unroll
  for (int tt = 0; tt < 4; ++tt) hacc[tt] = (f32x4){0.f, 0.f, 0.f, 0.f};
#pragma unroll
  for (int kt = 0; kt < 4; ++kt) {
    bf16x8 afr = load_frag((const float*)&y[r][kt * 32 + q * 8]);
#pragma unroll
    for (int tt = 0; tt < 4; ++tt) {
      const int col = w * 64 + tt * 16 + r;
      bf16x8 bfr = load_frag(W1 + (size_t)col * IN_F + kt * 32 + q * 8);
      hacc[tt] = __builtin_amdgcn_mfma_f32_16x16x32_bf16(afr, bfr, hacc[tt], 0, 0, 0);
    }
  }
#pragma unroll
  for (int tt = 0; tt < 4; ++tt) {
    const int col = w * 64 + tt * 16 + r;
    const float bias = b1[col];
#pragma unroll
    for (int i = 0; i < 4; ++i)
      h[q * 4 + i][col] = (__bf16)fmaxf(hacc[tt][i] + bias, 0.f);
  }
  __syncthreads();

  // g tile: wave w -> out cols [w*16, w*16+16), K=256
  f32x4 gacc = (f32x4){0.f, 0.f, 0.f, 0.f};
  const int o = w * 16 + r;
#pragma unroll
  for (int kt = 0; kt < 8; ++kt) {
    bf16x8 afr = *(const bf16x8*)&h[r][kt * 32 + q * 8];
    bf16x8 bfr = load_frag(W2 + (size_t)o * HID_F + kt * 32 + q * 8);
    gacc = __builtin_amdgcn_mfma_f32_16x16x32_bf16(afr, bfr, gacc, 0, 0, 0);
  }
#pragma unroll
  for (int i = 0; i < 4; ++i) gl[o][q * 4 + i] = gacc[i];
  __syncthreads();

  const int oo = t >> 2, r0 = (t & 3) * 4;
  bf16x4 ov;
#pragma unroll
  for (int rr = 0; rr < 4; ++rr) ov[rr] = (__bf16)(gl[oo][r0 + rr] * dl[r0 + rr]);
  *(bf16x4*)(Bt2 + (size_t)oo * N_NODES + j0 + r0) = ov;
}

// ---- k_out: out[j][o] = d[j]*sum_s P2 + b2[o] (vectorized f32x4) ----
__global__ __launch_bounds__(256) void k_out(const float* __restrict__ P2,
                                             const float* __restrict__ dvec,
                                             const float* __restrict__ b2,
                                             float* __restrict__ out) {
  const int idx = blockIdx.x * 256 + threadIdx.x;  // over N*OUT/4 vec4
  const int j = idx >> 4, o4 = idx & 15;
  const size_t plane4 = (size_t)N_NODES * OUT_F / 4;
  f32x4 s = (f32x4){0.f, 0.f, 0.f, 0.f};
#pragma unroll
  for (int sp = 0; sp < SPLIT2; ++sp) s += ((const f32x4*)P2)[idx + sp * plane4];
  s *= dvec[j];
  s += ((const f32x4*)b2)[o4];
  ((f32x4*)out)[idx] = s;
}

extern "C" void kernel_launch(void* const* d_in, const int* in_sizes, int n_in,
                              void* d_out, int out_size, void* d_ws,
                              size_t ws_size, hipStream_t stream) {
  const float* x   = (const float*)d_in[0];
  const float* adj = (const float*)d_in[1];
  const float* W1  = (const float*)d_in[2];
  const float* b1  = (const float*)d_in[3];
  const float* W2  = (const float*)d_in[4];
  const float* b2  = (const float*)d_in[5];
  float* out = (float*)d_out;
  char* ws = (char*)d_ws;

  size_t off = 0;
  __bf16* adjb = (__bf16*)(ws + off); off += (size_t)N_NODES * N_NODES * 2;  // 128Mi
  float*  dvec = (float*)(ws + off);  off += (size_t)N_NODES * 4;
  __bf16* Bt1  = (__bf16*)(ws + off); off += (size_t)IN_F * N_NODES * 2;
  float*  P1   = (float*)(ws + off);  off += (size_t)SPLIT1 * N_NODES * IN_F * 4;
  __bf16* Bt2  = (__bf16*)(ws + off); off += (size_t)OUT_F * N_NODES * 2;
  float*  P2   = (float*)(ws + off);  // +32Mi, total ~195 MiB

  hipLaunchKernelGGL(k_degcvt, dim3(N_NODES), dim3(256), 0, stream, adj, adjb, dvec);
  hipLaunchKernelGGL(k_bt1, dim3(N_NODES / 64), dim3(256), 0, stream, x, dvec, Bt1);
  // GEMM1: block 128x128, split-K=8 -> grid (64,8)
  hipLaunchKernelGGL((k_gemm_dma<2, 2, N_NODES / SPLIT1>),
                     dim3(N_NODES / 128, SPLIT1), dim3(256), 0, stream,
                     adjb, Bt1, P1);
  hipLaunchKernelGGL(k_red_mlp, dim3(N_NODES / 16), dim3(256), 0, stream, P1,
                     dvec, W1, b1, W2, Bt2);
  // GEMM2: block 256x64, split-K=16 -> grid (32,16)
  hipLaunchKernelGGL((k_gemm_dma<4, 1, N_NODES / SPLIT2>),
                     dim3(N_NODES / 256, SPLIT2), dim3(256), 0, stream,
                     adjb, Bt2, P2);
  hipLaunchKernelGGL(k_out, dim3((N_NODES * OUT_F / 4) / 256), dim3(256), 0,
                     stream, P2, dvec, b2, out);
}

// Round 3
// 478.467 us; speedup vs baseline: 1.0224x; 1.0224x over previous
//
#include <hip/hip_runtime.h>
#include <hip/hip_bf16.h>

typedef float f32x4 __attribute__((ext_vector_type(4)));
typedef __bf16 bf16x8 __attribute__((ext_vector_type(8)));
typedef __bf16 bf16x4 __attribute__((ext_vector_type(4)));

#define N_NODES 8192
#define IN_F    128
#define HID_F   256
#define OUT_F   64
#define SPLIT1  4
#define SPLIT2  8

// async global->LDS DMA, 16B per lane. LDS dst = wave-uniform base + lane*16.
// Generic LDS pointer's low 32 bits are the LDS byte offset on amdgcn.
__device__ __forceinline__ void dma16(const void* g, void* l) {
  __builtin_amdgcn_global_load_lds(
      (const __attribute__((address_space(1))) void*)g,
      (__attribute__((address_space(3))) void*)(uint32_t)(uintptr_t)l, 16, 0, 0);
}

// counted vmcnt wait — immediate must be a literal in the instruction text.
template <int K> __device__ __forceinline__ void wait_vmcnt() {
  if constexpr (K == 0)       asm volatile("s_waitcnt vmcnt(0)" ::: "memory");
  else if constexpr (K == 4)  asm volatile("s_waitcnt vmcnt(4)" ::: "memory");
  else if constexpr (K == 5)  asm volatile("s_waitcnt vmcnt(5)" ::: "memory");
  else if constexpr (K == 8)  asm volatile("s_waitcnt vmcnt(8)" ::: "memory");
  else if constexpr (K == 10) asm volatile("s_waitcnt vmcnt(10)" ::: "memory");
  else if constexpr (K == 12) asm volatile("s_waitcnt vmcnt(12)" ::: "memory");
  else if constexpr (K == 15) asm volatile("s_waitcnt vmcnt(15)" ::: "memory");
  else static_assert(K == 0, "unsupported vmcnt literal");
}

// ---- Kernel 1: deg rowsum + fp32->bf16 convert of adj into adjb ----
// 16B loads x2 and 16B stores per lane (bf16x8).
__global__ __launch_bounds__(256) void k_degcvt(const float* __restrict__ adj,
                                                __bf16* __restrict__ adjb,
                                                float* __restrict__ d) {
  const int row = blockIdx.x;
  const int t = threadIdx.x;
  const f32x4* p = (const f32x4*)(adj + (size_t)row * N_NODES);
  bf16x8* q = (bf16x8*)(adjb + (size_t)row * N_NODES);
  float s = 0.f;
#pragma unroll
  for (int i = 0; i < N_NODES / (256 * 8); ++i) {
    f32x4 a = p[i * 512 + 2 * t];
    f32x4 b = p[i * 512 + 2 * t + 1];
    s += a[0] + a[1] + a[2] + a[3] + b[0] + b[1] + b[2] + b[3];
    bf16x8 o = {(__bf16)a[0], (__bf16)a[1], (__bf16)a[2], (__bf16)a[3],
                (__bf16)b[0], (__bf16)b[1], (__bf16)b[2], (__bf16)b[3]};
    q[i * 256 + t] = o;
  }
#pragma unroll
  for (int off = 32; off > 0; off >>= 1) s += __shfl_down(s, off);
  __shared__ float red[4];
  if ((t & 63) == 0) red[t >> 6] = s;
  __syncthreads();
  if (t == 0) d[row] = rsqrtf(red[0] + red[1] + red[2] + red[3] + 1e-8f);
}

// ---- Kernel 2: Bt1[c][j] = bf16(d[j] * x[j][c]) ----
__global__ __launch_bounds__(256) void k_bt1(const float* __restrict__ x,
                                             const float* __restrict__ d,
                                             __bf16* __restrict__ Bt1) {
  __shared__ __bf16 tile[IN_F][64 + 2];
  const int t = threadIdx.x;
  const int j0 = blockIdx.x * 64;
#pragma unroll
  for (int rep = 0; rep < 32; ++rep) {
    int e = rep * 256 + t;
    int j = e >> 7, c = e & 127;
    tile[c][j] = (__bf16)(x[(size_t)(j0 + j) * IN_F + c] * d[j0 + j]);
  }
  __syncthreads();
#pragma unroll
  for (int rep = 0; rep < 32; ++rep) {
    int e = rep * 256 + t;
    int c = e >> 6, jj = e & 63;
    Bt1[(size_t)c * N_NODES + j0 + jj] = tile[c][jj];
  }
}

__device__ inline bf16x8 load_frag(const float* p) {
  f32x4 a = *(const f32x4*)p;
  f32x4 b = *(const f32x4*)(p + 4);
  bf16x8 o = {(__bf16)a[0], (__bf16)a[1], (__bf16)a[2], (__bf16)a[3],
              (__bf16)b[0], (__bf16)b[1], (__bf16)b[2], (__bf16)b[3]};
  return o;
}

// ---- one pipelined K-step of the DMA-staged GEMM ----
// 4-deep circular LDS pipeline, counted vmcnt (stages stay in flight across
// barriers). Buffer (t&3) is only overwritten by stage t+4, whose issue is
// fenced behind this iteration's trailing lgkmcnt(0)+s_barrier.
template <int WGM, int WGN, int KC, int KWAIT>
__device__ __forceinline__ void g_iter(char* sm, int t, int w,
                                       const __bf16* (&a_src)[WGM],
                                       const __bf16* (&b_src)[WGN],
                                       const int (&offA)[4],
                                       const int (&offB)[4],
                                       f32x4 (&acc)[4][4]) {
  constexpr int BM = WGM * 64, BN = WGN * 64;
  constexpr int ABYTES = BM * 64;
  constexpr int STAGE = (BM + BN) * 64;
  constexpr int NIT = KC / 32;

  if (t + 3 < NIT) {  // issue stage t+3 into buf[(t+3)&3]
    char* nb = sm + ((t + 3) & 3) * STAGE;
#pragma unroll
    for (int kk = 0; kk < WGM; ++kk) {
      dma16(a_src[kk], nb + kk * 4096 + (w << 10));
      a_src[kk] += 32;
    }
#pragma unroll
    for (int kk = 0; kk < WGN; ++kk) {
      dma16(b_src[kk], nb + ABYTES + kk * 4096 + (w << 10));
      b_src[kk] += 32;
    }
  }
  // pin DMA issues above the counted wait (count correctness depends on it)
  __builtin_amdgcn_sched_barrier(0);
  wait_vmcnt<KWAIT>();                       // stage t complete (this wave)
  asm volatile("s_barrier" ::: "memory");    // stage t complete (all waves)
  __builtin_amdgcn_sched_barrier(0);         // keep ds_reads below barrier

  const char* cb = sm + (t & 3) * STAGE;
  bf16x8 af[4], bfr[4];
#pragma unroll
  for (int tm = 0; tm < 4; ++tm) af[tm] = *(const bf16x8*)(cb + offA[tm]);
#pragma unroll
  for (int ct = 0; ct < 4; ++ct) bfr[ct] = *(const bf16x8*)(cb + offB[ct]);
#pragma unroll
  for (int tm = 0; tm < 4; ++tm)
#pragma unroll
    for (int ct = 0; ct < 4; ++ct)
      acc[tm][ct] = __builtin_amdgcn_mfma_f32_16x16x32_bf16(
          af[tm], bfr[ct], acc[tm][ct], 0, 0, 0);

  // reads of buf[t&3] landed before anyone may issue stage t+4 (next iter)
  __builtin_amdgcn_sched_barrier(0);
  asm volatile("s_waitcnt lgkmcnt(0)" ::: "memory");
  asm volatile("s_barrier" ::: "memory");
}

// ---- DMA-staged MFMA GEMM partials: P[s][m][c] = adj_tile @ Bt^T ----
// Block tile: BM x BN (BM=WGM*64, BN=WGN*64), 4 waves in WGM x WGN grid,
// wave tile 64x64 (TM=4,NT=4). K-chunk KC per blockIdx.y. LDS 4-deep circular,
// staged via global_load_lds w/ chunk swizzle c ^= (row>>1)&3 (bank-friendly).
template <int WGM, int WGN, int KC>
__global__ __launch_bounds__(256, 2) void k_gemm_dma(
    const __bf16* __restrict__ A, const __bf16* __restrict__ Bt,
    float* __restrict__ P) {
  constexpr int BM = WGM * 64, BN = WGN * 64;
  constexpr int ANI = BM / 64, BNI = BN / 64;   // staging instrs per thread
  constexpr int ABYTES = BM * 64;               // A region bytes per stage
  constexpr int STAGE = (BM + BN) * 64;         // one stage buffer
  constexpr int NIT = KC / 32;
  constexpr int L = ANI + BNI;                  // vm loads/thread/stage
  static_assert(NIT > 3, "pipeline needs >3 K-steps");

  __shared__ __align__(16) char sm[4 * STAGE];

  const int t = threadIdx.x;
  const int w = t >> 6, lane = t & 63;
  const int r = lane & 15, q = lane >> 4;
  const int wm = (WGN == 1) ? w : (w >> 1);
  const int wn = (WGN == 1) ? 0 : (w & 1);
  const int m0 = blockIdx.x * BM;
  const int ks = blockIdx.y;
  const int k0 = ks * KC;

  // staging source pointers (per-thread): chunk L = kk*256 + t -> row n=L>>2,
  // chunk slot c=L&3, stored swizzled: holds global chunk c ^ ((n>>1)&3).
  const int n_ = t >> 2;
  const int csw = (t & 3) ^ ((t >> 3) & 3);
  const __bf16* a_src[ANI];
  const __bf16* b_src[BNI];
#pragma unroll
  for (int kk = 0; kk < ANI; ++kk)
    a_src[kk] = A + (size_t)(m0 + n_ + 64 * kk) * N_NODES + k0 + csw * 8;
#pragma unroll
  for (int kk = 0; kk < BNI; ++kk)
    b_src[kk] = Bt + (size_t)(n_ + 64 * kk) * N_NODES + k0 + csw * 8;

  // fragment LDS byte offsets (loop-invariant): row*64 + (q^((row>>1)&3))*16
  int offA[4], offB[4];
#pragma unroll
  for (int tm = 0; tm < 4; ++tm) {
    const int row = wm * 64 + tm * 16 + r;
    offA[tm] = row * 64 + ((q ^ ((row >> 1) & 3)) << 4);
  }
#pragma unroll
  for (int ct = 0; ct < 4; ++ct) {
    const int row = wn * 64 + ct * 16 + r;
    offB[ct] = ABYTES + row * 64 + ((q ^ ((row >> 1) & 3)) << 4);
  }

  f32x4 acc[4][4];
#pragma unroll
  for (int tm = 0; tm < 4; ++tm)
#pragma unroll
    for (int ct = 0; ct < 4; ++ct) acc[tm][ct] = (f32x4){0.f, 0.f, 0.f, 0.f};

  // prologue: fill stages 0..2
#pragma unroll
  for (int s = 0; s < 3; ++s) {
    char* sb = sm + s * STAGE;
#pragma unroll
    for (int kk = 0; kk < ANI; ++kk) {
      dma16(a_src[kk], sb + kk * 4096 + (w << 10));
      a_src[kk] += 32;
    }
#pragma unroll
    for (int kk = 0; kk < BNI; ++kk) {
      dma16(b_src[kk], sb + ABYTES + kk * 4096 + (w << 10));
      b_src[kk] += 32;
    }
  }

  for (int it = 0; it < NIT - 3; ++it)
    g_iter<WGM, WGN, KC, 3 * L>(sm, it, w, a_src, b_src, offA, offB, acc);
  g_iter<WGM, WGN, KC, 2 * L>(sm, NIT - 3, w, a_src, b_src, offA, offB, acc);
  g_iter<WGM, WGN, KC, L>(sm, NIT - 2, w, a_src, b_src, offA, offB, acc);
  g_iter<WGM, WGN, KC, 0>(sm, NIT - 1, w, a_src, b_src, offA, offB, acc);

  // epilogue: C/D layout col=lane&15, row=q*4+reg
  float* pout =
      P + ((size_t)ks * N_NODES + m0 + wm * 64 + q * 4) * BN + wn * 64 + r;
#pragma unroll
  for (int tm = 0; tm < 4; ++tm)
#pragma unroll
    for (int ct = 0; ct < 4; ++ct)
#pragma unroll
      for (int i = 0; i < 4; ++i)
        pout[(size_t)(tm * 16 + i) * BN + ct * 16] = acc[tm][ct][i];
}

// ---- reduce P1 + MLP (bf16 MFMA) + build Bt2, 16 nodes per block ----
__global__ __launch_bounds__(256) void k_red_mlp(const float* __restrict__ P1,
                                                 const float* __restrict__ dvec,
                                                 const float* __restrict__ W1,
                                                 const float* __restrict__ b1,
                                                 const float* __restrict__ W2,
                                                 __bf16* __restrict__ Bt2) {
  __shared__ __align__(16) float y[16][IN_F + 4];
  __shared__ __align__(16) __bf16 h[16][HID_F + 8];
  __shared__ __align__(16) float gl[OUT_F][20];
  __shared__ float dl[16];
  const int t = threadIdx.x;
  const int lane = t & 63;
  const int w = t >> 6;
  const int r = lane & 15, q = lane >> 4;
  const int j0 = blockIdx.x * 16;

  if (t < 16) dl[t] = dvec[j0 + t];
  const size_t plane4 = (size_t)N_NODES * IN_F / 4;
  for (int e = t; e < 16 * IN_F / 4; e += 256) {
    const int jj = e >> 5, c4 = e & 31;
    const size_t base = (size_t)(j0 + jj) * (IN_F / 4) + c4;
    f32x4 v = (f32x4){0.f, 0.f, 0.f, 0.f};
#pragma unroll
    for (int s = 0; s < SPLIT1; ++s) v += ((const f32x4*)P1)[base + s * plane4];
    const float dj = dvec[j0 + jj];
    v *= dj;
    *(f32x4*)&y[jj][c4 * 4] = v;
  }
  __syncthreads();

  // h tile: wave w -> hid cols [w*64, w*64+64)
  f32x4 hacc[4];
#pragma unroll
  for (int tt = 0; tt < 4; ++tt) hacc[tt] = (f32x4){0.f, 0.f, 0.f, 0.f};
#pragma unroll
  for (int kt = 0; kt < 4; ++kt) {
    bf16x8 afr = load_frag((const float*)&y[r][kt * 32 + q * 8]);
#pragma unroll
    for (int tt = 0; tt < 4; ++tt) {
      const int col = w * 64 + tt * 16 + r;
      bf16x8 bfr = load_frag(W1 + (size_t)col * IN_F + kt * 32 + q * 8);
      hacc[tt] = __builtin_amdgcn_mfma_f32_16x16x32_bf16(afr, bfr, hacc[tt], 0, 0, 0);
    }
  }
#pragma unroll
  for (int tt = 0; tt < 4; ++tt) {
    const int col = w * 64 + tt * 16 + r;
    const float bias = b1[col];
#pragma unroll
    for (int i = 0; i < 4; ++i)
      h[q * 4 + i][col] = (__bf16)fmaxf(hacc[tt][i] + bias, 0.f);
  }
  __syncthreads();

  // g tile: wave w -> out cols [w*16, w*16+16), K=256
  f32x4 gacc = (f32x4){0.f, 0.f, 0.f, 0.f};
  const int o = w * 16 + r;
#pragma unroll
  for (int kt = 0; kt < 8; ++kt) {
    bf16x8 afr = *(const bf16x8*)&h[r][kt * 32 + q * 8];
    bf16x8 bfr = load_frag(W2 + (size_t)o * HID_F + kt * 32 + q * 8);
    gacc = __builtin_amdgcn_mfma_f32_16x16x32_bf16(afr, bfr, gacc, 0, 0, 0);
  }
#pragma unroll
  for (int i = 0; i < 4; ++i) gl[o][q * 4 + i] = gacc[i];
  __syncthreads();

  const int oo = t >> 2, r0 = (t & 3) * 4;
  bf16x4 ov;
#pragma unroll
  for (int rr = 0; rr < 4; ++rr) ov[rr] = (__bf16)(gl[oo][r0 + rr] * dl[r0 + rr]);
  *(bf16x4*)(Bt2 + (size_t)oo * N_NODES + j0 + r0) = ov;
}

// ---- k_out: out[j][o] = d[j]*sum_s P2 + b2[o] (vectorized f32x4) ----
__global__ __launch_bounds__(256) void k_out(const float* __restrict__ P2,
                                             const float* __restrict__ dvec,
                                             const float* __restrict__ b2,
                                             float* __restrict__ out) {
  const int idx = blockIdx.x * 256 + threadIdx.x;  // over N*OUT/4 vec4
  const int j = idx >> 4, o4 = idx & 15;
  const size_t plane4 = (size_t)N_NODES * OUT_F / 4;
  f32x4 s = (f32x4){0.f, 0.f, 0.f, 0.f};
#pragma unroll
  for (int sp = 0; sp < SPLIT2; ++sp) s += ((const f32x4*)P2)[idx + sp * plane4];
  s *= dvec[j];
  s += ((const f32x4*)b2)[o4];
  ((f32x4*)out)[idx] = s;
}

extern "C" void kernel_launch(void* const* d_in, const int* in_sizes, int n_in,
                              void* d_out, int out_size, void* d_ws,
                              size_t ws_size, hipStream_t stream) {
  const float* x   = (const float*)d_in[0];
  const float* adj = (const float*)d_in[1];
  const float* W1  = (const float*)d_in[2];
  const float* b1  = (const float*)d_in[3];
  const float* W2  = (const float*)d_in[4];
  const float* b2  = (const float*)d_in[5];
  float* out = (float*)d_out;
  char* ws = (char*)d_ws;

  size_t off = 0;
  __bf16* adjb = (__bf16*)(ws + off); off += (size_t)N_NODES * N_NODES * 2;  // 128Mi
  float*  dvec = (float*)(ws + off);  off += (size_t)N_NODES * 4;
  __bf16* Bt1  = (__bf16*)(ws + off); off += (size_t)IN_F * N_NODES * 2;
  float*  P1   = (float*)(ws + off);  off += (size_t)SPLIT1 * N_NODES * IN_F * 4;
  __bf16* Bt2  = (__bf16*)(ws + off); off += (size_t)OUT_F * N_NODES * 2;
  float*  P2   = (float*)(ws + off);  // total ~163 MiB

  hipLaunchKernelGGL(k_degcvt, dim3(N_NODES), dim3(256), 0, stream, adj, adjb, dvec);
  hipLaunchKernelGGL(k_bt1, dim3(N_NODES / 64), dim3(256), 0, stream, x, dvec, Bt1);
  // GEMM1: block 128x128, split-K=4 -> grid (64,4)
  hipLaunchKernelGGL((k_gemm_dma<2, 2, N_NODES / SPLIT1>),
                     dim3(N_NODES / 128, SPLIT1), dim3(256), 0, stream,
                     adjb, Bt1, P1);
  hipLaunchKernelGGL(k_red_mlp, dim3(N_NODES / 16), dim3(256), 0, stream, P1,
                     dvec, W1, b1, W2, Bt2);
  // GEMM2: block 256x64, split-K=8 -> grid (32,8)
  hipLaunchKernelGGL((k_gemm_dma<4, 1, N_NODES / SPLIT2>),
                     dim3(N_NODES / 256, SPLIT2), dim3(256), 0, stream,
                     adjb, Bt2, P2);
  hipLaunchKernelGGL(k_out, dim3((N_NODES * OUT_F / 4) / 256), dim3(256), 0,
                     stream, P2, dvec, b2, out);
}

// Round 4
// 459.031 us; speedup vs baseline: 1.0657x; 1.0423x over previous
//
#include <hip/hip_runtime.h>
#include <hip/hip_bf16.h>

typedef float f32x4 __attribute__((ext_vector_type(4)));
typedef int   i32x4 __attribute__((ext_vector_type(4)));
typedef int   i32x2 __attribute__((ext_vector_type(2)));
typedef __bf16 bf16x8 __attribute__((ext_vector_type(8)));

#define N_NODES 8192
#define IN_F    128
#define HID_F   256
#define OUT_F   64
#define SPLIT1  4
#define SPLIT2  8

// async global->LDS DMA, 16B per lane. LDS dst = wave-uniform base + lane*16.
__device__ __forceinline__ void dma16(const void* g, void* l) {
  __builtin_amdgcn_global_load_lds(
      (const __attribute__((address_space(1))) void*)g,
      (__attribute__((address_space(3))) void*)(uint32_t)(uintptr_t)l, 16, 0, 0);
}

// counted vmcnt wait — immediate must be a literal in the instruction text.
template <int K> __device__ __forceinline__ void wait_vmcnt() {
  if constexpr (K == 0)       asm volatile("s_waitcnt vmcnt(0)" ::: "memory");
  else if constexpr (K == 6)  asm volatile("s_waitcnt vmcnt(6)" ::: "memory");
  else if constexpr (K == 12) asm volatile("s_waitcnt vmcnt(12)" ::: "memory");
  else if constexpr (K == 18) asm volatile("s_waitcnt vmcnt(18)" ::: "memory");
  else static_assert(K == 0, "unsupported vmcnt literal");
}

// ---- Kernel 1: deg rowsum + fp32->i8 quantize of adj (zero-point 127) ----
// adj in [0,1): q = rint(254*adj - 127) in [-127,127]; A = (q+127)/254.
__global__ __launch_bounds__(256) void k_degcvt(const float* __restrict__ adj,
                                                char* __restrict__ adjq,
                                                float* __restrict__ d) {
  const int row = blockIdx.x;
  const int t = threadIdx.x;
  const f32x4* p = (const f32x4*)(adj + (size_t)row * N_NODES);
  i32x2* qo = (i32x2*)(adjq + (size_t)row * N_NODES);
  float s = 0.f;
#pragma unroll
  for (int i = 0; i < N_NODES / (256 * 8); ++i) {
    f32x4 a = p[i * 512 + 2 * t];
    f32x4 b = p[i * 512 + 2 * t + 1];
    s += a[0] + a[1] + a[2] + a[3] + b[0] + b[1] + b[2] + b[3];
    int q0 = __float2int_rn(fmaf(a[0], 254.f, -127.f));
    int q1 = __float2int_rn(fmaf(a[1], 254.f, -127.f));
    int q2 = __float2int_rn(fmaf(a[2], 254.f, -127.f));
    int q3 = __float2int_rn(fmaf(a[3], 254.f, -127.f));
    int q4 = __float2int_rn(fmaf(b[0], 254.f, -127.f));
    int q5 = __float2int_rn(fmaf(b[1], 254.f, -127.f));
    int q6 = __float2int_rn(fmaf(b[2], 254.f, -127.f));
    int q7 = __float2int_rn(fmaf(b[3], 254.f, -127.f));
    i32x2 o;
    o[0] = (q0 & 255) | ((q1 & 255) << 8) | ((q2 & 255) << 16) | ((q3 & 255) << 24);
    o[1] = (q4 & 255) | ((q5 & 255) << 8) | ((q6 & 255) << 16) | ((q7 & 255) << 24);
    qo[i * 256 + t] = o;
  }
#pragma unroll
  for (int off = 32; off > 0; off >>= 1) s += __shfl_down(s, off);
  __shared__ float red[4];
  if ((t & 63) == 0) red[t >> 6] = s;
  __syncthreads();
  if (t == 0) d[row] = rsqrtf(red[0] + red[1] + red[2] + red[3] + 1e-8f);
}

// ---- Kernel 2: per-feature-c hi/lo i8 quantize of B1[c][j] = d[j]*x[j][c] ----
// per-column scale s1 = max|v|/127, s2 = s1/254; also per-split-chunk true
// colsums csv[ks][c] (for the A zero-point correction).
__global__ __launch_bounds__(256) void k_bt1q(const float* __restrict__ x,
                                              const float* __restrict__ d,
                                              char* __restrict__ Q1,
                                              char* __restrict__ Q2,
                                              float* __restrict__ s1v,
                                              float* __restrict__ s2v,
                                              float* __restrict__ csv) {
  __shared__ float col[N_NODES];  // 32 KB
  __shared__ float redmx[4];
  __shared__ float ps[4][SPLIT1];
  const int c = blockIdx.x, t = threadIdx.x;
  float mx = 0.f;
#pragma unroll
  for (int i = 0; i < 8; ++i) {
    const int j0 = i * 1024 + t * 4;
#pragma unroll
    for (int k = 0; k < 4; ++k) {
      float v = x[(size_t)(j0 + k) * IN_F + c] * d[j0 + k];
      col[j0 + k] = v;
      mx = fmaxf(mx, fabsf(v));
    }
  }
#pragma unroll
  for (int off = 32; off > 0; off >>= 1) mx = fmaxf(mx, __shfl_down(mx, off));
  if ((t & 63) == 0) redmx[t >> 6] = mx;
  __syncthreads();
  mx = fmaxf(fmaxf(redmx[0], redmx[1]), fmaxf(redmx[2], redmx[3]));
  mx = fmaxf(mx, 1e-20f);
  const float s1 = mx * (1.f / 127.f);
  const float s2 = s1 * (1.f / 254.f);
  const float r1 = 127.f / mx;
  const float r2 = r1 * 254.f;
  if (t == 0) { s1v[c] = s1; s2v[c] = s2; }
  float psum[2] = {0.f, 0.f};  // chunk pairs handled via i>>1 (compile-time)
  float pall[SPLIT1] = {0.f, 0.f, 0.f, 0.f};
#pragma unroll
  for (int i = 0; i < 8; ++i) {
    const int j0 = i * 1024 + t * 4;
    int w1 = 0, w2 = 0;
    float vs = 0.f;
#pragma unroll
    for (int k = 0; k < 4; ++k) {
      float v = col[j0 + k];
      int q1 = __float2int_rn(v * r1);
      float resid = fmaf(-s1, (float)q1, v);
      int q2 = __float2int_rn(resid * r2);
      w1 |= (q1 & 255) << (8 * k);
      w2 |= (q2 & 255) << (8 * k);
      vs += v;
    }
    *(int*)(Q1 + (size_t)c * N_NODES + j0) = w1;
    *(int*)(Q2 + (size_t)c * N_NODES + j0) = w2;
    pall[i >> 1] += vs;  // chunk = j0>>11 = i>>1 (t*4 <= 1020 < 1024)
  }
  (void)psum;
#pragma unroll
  for (int ks = 0; ks < SPLIT1; ++ks)
#pragma unroll
    for (int off = 32; off > 0; off >>= 1) pall[ks] += __shfl_down(pall[ks], off);
  if ((t & 63) == 0) {
#pragma unroll
    for (int ks = 0; ks < SPLIT1; ++ks) ps[t >> 6][ks] = pall[ks];
  }
  __syncthreads();
  if (t < SPLIT1) csv[t * IN_F + c] = ps[0][t] + ps[1][t] + ps[2][t] + ps[3][t];
}

__device__ inline bf16x8 load_frag(const float* p) {
  f32x4 a = *(const f32x4*)p;
  f32x4 b = *(const f32x4*)(p + 4);
  bf16x8 o = {(__bf16)a[0], (__bf16)a[1], (__bf16)a[2], (__bf16)a[3],
              (__bf16)b[0], (__bf16)b[1], (__bf16)b[2], (__bf16)b[3]};
  return o;
}

// ---- one pipelined K-step of the i8 DMA-staged GEMM ----
// 4-deep circular LDS pipeline, counted vmcnt. K-step = 64 i8 = 64 B/row
// (same byte geometry as the old 32xbf16). Two B planes (hi/lo).
template <int WGM, int WGN, int KC, int KWAIT>
__device__ __forceinline__ void g_iter(char* sm, int it, int w,
                                       const char* (&a_src)[WGM],
                                       const char* (&b1_src)[WGN],
                                       const char* (&b2_src)[WGN],
                                       const int (&offA)[4],
                                       const int (&offB)[4],
                                       i32x4 (&acc1)[4][4],
                                       i32x4 (&acc2)[4][4]) {
  constexpr int BM = WGM * 64, BN = WGN * 64;
  constexpr int ABYTES = BM * 64;
  constexpr int B2OFF = ABYTES + BN * 64;
  constexpr int STAGE = (BM + 2 * BN) * 64;
  constexpr int NIT = KC / 64;

  if (it + 3 < NIT) {  // issue stage it+3 into buf[(it+3)&3]
    char* nb = sm + ((it + 3) & 3) * STAGE;
#pragma unroll
    for (int kk = 0; kk < WGM; ++kk) {
      dma16(a_src[kk], nb + kk * 4096 + (w << 10));
      a_src[kk] += 64;
    }
#pragma unroll
    for (int kk = 0; kk < WGN; ++kk) {
      dma16(b1_src[kk], nb + ABYTES + kk * 4096 + (w << 10));
      b1_src[kk] += 64;
    }
#pragma unroll
    for (int kk = 0; kk < WGN; ++kk) {
      dma16(b2_src[kk], nb + B2OFF + kk * 4096 + (w << 10));
      b2_src[kk] += 64;
    }
  }
  __builtin_amdgcn_sched_barrier(0);
  wait_vmcnt<KWAIT>();                       // stage it complete (this wave)
  asm volatile("s_barrier" ::: "memory");    // stage it complete (all waves)
  __builtin_amdgcn_sched_barrier(0);

  const char* cb = sm + (it & 3) * STAGE;
  i32x4 af[4], b1f[4], b2f[4];
#pragma unroll
  for (int tm = 0; tm < 4; ++tm) af[tm] = *(const i32x4*)(cb + offA[tm]);
#pragma unroll
  for (int ct = 0; ct < 4; ++ct) {
    b1f[ct] = *(const i32x4*)(cb + offB[ct]);
    b2f[ct] = *(const i32x4*)(cb + offB[ct] + BN * 64);
  }
#pragma unroll
  for (int tm = 0; tm < 4; ++tm)
#pragma unroll
    for (int ct = 0; ct < 4; ++ct) {
      acc1[tm][ct] = __builtin_amdgcn_mfma_i32_16x16x64_i8(af[tm], b1f[ct],
                                                           acc1[tm][ct], 0, 0, 0);
      acc2[tm][ct] = __builtin_amdgcn_mfma_i32_16x16x64_i8(af[tm], b2f[ct],
                                                           acc2[tm][ct], 0, 0, 0);
    }
  __builtin_amdgcn_sched_barrier(0);
  asm volatile("s_waitcnt lgkmcnt(0)" ::: "memory");
  asm volatile("s_barrier" ::: "memory");
}

// ---- i8 DMA-staged MFMA GEMM partials: P[s][m][c] (dequantized f32) ----
// P = (s1[c]*Qa@Q1 + s2[c]*Qa@Q2 + 127*csv[ks][c]) / 254
template <int WGM, int WGN, int KC>
__global__ __launch_bounds__(256, 1) void k_gemm_i8(
    const char* __restrict__ A, const char* __restrict__ B1,
    const char* __restrict__ B2, const float* __restrict__ s1v,
    const float* __restrict__ s2v, const float* __restrict__ csv,
    float* __restrict__ P) {
  constexpr int BM = WGM * 64, BN = WGN * 64;
  constexpr int ANI = WGM, BNI = WGN;
  constexpr int ABYTES = BM * 64;
  constexpr int STAGE = (BM + 2 * BN) * 64;
  constexpr int NIT = KC / 64;
  constexpr int L = ANI + 2 * BNI;  // vm loads/thread/stage
  static_assert(NIT > 3, "pipeline needs >3 K-steps");
  static_assert(L == 6, "wait literals assume L==6");

  __shared__ __align__(16) char sm[4 * STAGE];

  const int t = threadIdx.x;
  const int w = t >> 6, lane = t & 63;
  const int r = lane & 15, q = lane >> 4;
  const int wm = (WGN == 1) ? w : (w >> 1);
  const int wn = (WGN == 1) ? 0 : (w & 1);
  const int m0 = blockIdx.x * BM;
  const int ks = blockIdx.y;
  const int k0 = ks * KC;

  // staging sources: row n_ = t>>2, 16B slot csw (chunk-swizzled in 16B units)
  const int n_ = t >> 2;
  const int csw = (t & 3) ^ ((t >> 3) & 3);
  const char* a_src[ANI];
  const char* b1_src[BNI];
  const char* b2_src[BNI];
#pragma unroll
  for (int kk = 0; kk < ANI; ++kk)
    a_src[kk] = A + (size_t)(m0 + n_ + 64 * kk) * N_NODES + k0 + csw * 16;
#pragma unroll
  for (int kk = 0; kk < BNI; ++kk) {
    b1_src[kk] = B1 + (size_t)(n_ + 64 * kk) * N_NODES + k0 + csw * 16;
    b2_src[kk] = B2 + (size_t)(n_ + 64 * kk) * N_NODES + k0 + csw * 16;
  }

  // fragment LDS byte offsets: row*64 + (q^((row>>1)&3))*16
  int offA[4], offB[4];
#pragma unroll
  for (int tm = 0; tm < 4; ++tm) {
    const int row = wm * 64 + tm * 16 + r;
    offA[tm] = row * 64 + ((q ^ ((row >> 1) & 3)) << 4);
  }
#pragma unroll
  for (int ct = 0; ct < 4; ++ct) {
    const int row = wn * 64 + ct * 16 + r;
    offB[ct] = ABYTES + row * 64 + ((q ^ ((row >> 1) & 3)) << 4);
  }

  i32x4 acc1[4][4], acc2[4][4];
#pragma unroll
  for (int tm = 0; tm < 4; ++tm)
#pragma unroll
    for (int ct = 0; ct < 4; ++ct) {
      acc1[tm][ct] = (i32x4){0, 0, 0, 0};
      acc2[tm][ct] = (i32x4){0, 0, 0, 0};
    }

  // prologue: fill stages 0..2
#pragma unroll
  for (int s = 0; s < 3; ++s) {
    char* sb = sm + s * STAGE;
#pragma unroll
    for (int kk = 0; kk < ANI; ++kk) {
      dma16(a_src[kk], sb + kk * 4096 + (w << 10));
      a_src[kk] += 64;
    }
#pragma unroll
    for (int kk = 0; kk < BNI; ++kk) {
      dma16(b1_src[kk], sb + ABYTES + kk * 4096 + (w << 10));
      b1_src[kk] += 64;
    }
#pragma unroll
    for (int kk = 0; kk < BNI; ++kk) {
      dma16(b2_src[kk], sb + ABYTES + BN * 64 + kk * 4096 + (w << 10));
      b2_src[kk] += 64;
    }
  }

  for (int it = 0; it < NIT - 3; ++it)
    g_iter<WGM, WGN, KC, 18>(sm, it, w, a_src, b1_src, b2_src, offA, offB, acc1, acc2);
  g_iter<WGM, WGN, KC, 12>(sm, NIT - 3, w, a_src, b1_src, b2_src, offA, offB, acc1, acc2);
  g_iter<WGM, WGN, KC, 6>(sm, NIT - 2, w, a_src, b1_src, b2_src, offA, offB, acc1, acc2);
  g_iter<WGM, WGN, KC, 0>(sm, NIT - 1, w, a_src, b1_src, b2_src, offA, offB, acc1, acc2);

  // epilogue: dequant. C/D layout col=lane&15, row=q*4+reg
  float* pout =
      P + ((size_t)ks * N_NODES + m0 + wm * 64 + q * 4) * BN + wn * 64 + r;
#pragma unroll
  for (int ct = 0; ct < 4; ++ct) {
    const int col = wn * 64 + ct * 16 + r;
    const float s1c = s1v[col];
    const float s2c = s2v[col];
    const float corr = 127.f * csv[ks * BN + col];
#pragma unroll
    for (int tm = 0; tm < 4; ++tm)
#pragma unroll
      for (int i = 0; i < 4; ++i)
        pout[(size_t)(tm * 16 + i) * BN + ct * 16] =
            (s1c * (float)acc1[tm][ct][i] + s2c * (float)acc2[tm][ct][i] + corr) *
            (1.f / 254.f);
  }
}

// ---- reduce P1 + MLP (bf16 MFMA) + write Gf[o][j] = d[j]*g (f32) ----
__global__ __launch_bounds__(256) void k_red_mlp(const float* __restrict__ P1,
                                                 const float* __restrict__ dvec,
                                                 const float* __restrict__ W1,
                                                 const float* __restrict__ b1,
                                                 const float* __restrict__ W2,
                                                 float* __restrict__ Gf) {
  __shared__ __align__(16) float y[16][IN_F + 4];
  __shared__ __align__(16) __bf16 h[16][HID_F + 8];
  __shared__ __align__(16) float gl[OUT_F][20];
  __shared__ float dl[16];
  const int t = threadIdx.x;
  const int lane = t & 63;
  const int w = t >> 6;
  const int r = lane & 15, q = lane >> 4;
  const int j0 = blockIdx.x * 16;

  if (t < 16) dl[t] = dvec[j0 + t];
  const size_t plane4 = (size_t)N_NODES * IN_F / 4;
  for (int e = t; e < 16 * IN_F / 4; e += 256) {
    const int jj = e >> 5, c4 = e & 31;
    const size_t base = (size_t)(j0 + jj) * (IN_F / 4) + c4;
    f32x4 v = (f32x4){0.f, 0.f, 0.f, 0.f};
#pragma unroll
    for (int s = 0; s < SPLIT1; ++s) v += ((const f32x4*)P1)[base + s * plane4];
    const float dj = dvec[j0 + jj];
    v *= dj;
    *(f32x4*)&y[jj][c4 * 4] = v;
  }
  __syncthreads();

  // h tile: wave w -> hid cols [w*64, w*64+64)
  f32x4 hacc[4];
#pragma unroll
  for (int tt = 0; tt < 4; ++tt) hacc[tt] = (f32x4){0.f, 0.f, 0.f, 0.f};
#pragma unroll
  for (int kt = 0; kt < 4; ++kt) {
    bf16x8 afr = load_frag((const float*)&y[r][kt * 32 + q * 8]);
#pragma unroll
    for (int tt = 0; tt < 4; ++tt) {
      const int col = w * 64 + tt * 16 + r;
      bf16x8 bfr = load_frag(W1 + (size_t)col * IN_F + kt * 32 + q * 8);
      hacc[tt] = __builtin_amdgcn_mfma_f32_16x16x32_bf16(afr, bfr, hacc[tt], 0, 0, 0);
    }
  }
#pragma unroll
  for (int tt = 0; tt < 4; ++tt) {
    const int col = w * 64 + tt * 16 + r;
    const float bias = b1[col];
#pragma unroll
    for (int i = 0; i < 4; ++i)
      h[q * 4 + i][col] = (__bf16)fmaxf(hacc[tt][i] + bias, 0.f);
  }
  __syncthreads();

  // g tile: wave w -> out cols [w*16, w*16+16), K=256
  f32x4 gacc = (f32x4){0.f, 0.f, 0.f, 0.f};
  const int o = w * 16 + r;
#pragma unroll
  for (int kt = 0; kt < 8; ++kt) {
    bf16x8 afr = *(const bf16x8*)&h[r][kt * 32 + q * 8];
    bf16x8 bfr = load_frag(W2 + (size_t)o * HID_F + kt * 32 + q * 8);
    gacc = __builtin_amdgcn_mfma_f32_16x16x32_bf16(afr, bfr, gacc, 0, 0, 0);
  }
#pragma unroll
  for (int i = 0; i < 4; ++i) gl[o][q * 4 + i] = gacc[i];
  __syncthreads();

  const int oo = t >> 2, r0 = (t & 3) * 4;
  f32x4 ov;
#pragma unroll
  for (int rr = 0; rr < 4; ++rr) ov[rr] = gl[oo][r0 + rr] * dl[r0 + rr];
  *(f32x4*)(Gf + (size_t)oo * N_NODES + j0 + r0) = ov;
}

// ---- per-o hi/lo i8 quantize of B2[o][j] = Gf[o][j] + chunk colsums ----
__global__ __launch_bounds__(256) void k_quant2(const float* __restrict__ G,
                                                char* __restrict__ Q1,
                                                char* __restrict__ Q2,
                                                float* __restrict__ s1v,
                                                float* __restrict__ s2v,
                                                float* __restrict__ csv) {
  __shared__ float redmx[4];
  __shared__ float ps[4][SPLIT2];
  const int o = blockIdx.x, t = threadIdx.x;
  const float* row = G + (size_t)o * N_NODES;
  f32x4 vv[8];
  float mx = 0.f;
#pragma unroll
  for (int i = 0; i < 8; ++i) {
    vv[i] = ((const f32x4*)row)[i * 256 + t];
    mx = fmaxf(mx, fmaxf(fmaxf(fabsf(vv[i][0]), fabsf(vv[i][1])),
                         fmaxf(fabsf(vv[i][2]), fabsf(vv[i][3]))));
  }
#pragma unroll
  for (int off = 32; off > 0; off >>= 1) mx = fmaxf(mx, __shfl_down(mx, off));
  if ((t & 63) == 0) redmx[t >> 6] = mx;
  __syncthreads();
  mx = fmaxf(fmaxf(redmx[0], redmx[1]), fmaxf(redmx[2], redmx[3]));
  mx = fmaxf(mx, 1e-20f);
  const float s1 = mx * (1.f / 127.f);
  const float s2 = s1 * (1.f / 254.f);
  const float r1 = 127.f / mx;
  const float r2 = r1 * 254.f;
  if (t == 0) { s1v[o] = s1; s2v[o] = s2; }
  float pall[SPLIT2] = {};
#pragma unroll
  for (int i = 0; i < 8; ++i) {
    const int j0 = i * 1024 + t * 4;
    int w1 = 0, w2 = 0;
    float vs = 0.f;
#pragma unroll
    for (int k = 0; k < 4; ++k) {
      float v = vv[i][k];
      int q1 = __float2int_rn(v * r1);
      float resid = fmaf(-s1, (float)q1, v);
      int q2 = __float2int_rn(resid * r2);
      w1 |= (q1 & 255) << (8 * k);
      w2 |= (q2 & 255) << (8 * k);
      vs += v;
    }
    *(int*)(Q1 + (size_t)o * N_NODES + j0) = w1;
    *(int*)(Q2 + (size_t)o * N_NODES + j0) = w2;
    pall[i] += vs;  // chunk = j0>>10 = i
  }
#pragma unroll
  for (int ks = 0; ks < SPLIT2; ++ks)
#pragma unroll
    for (int off = 32; off > 0; off >>= 1) pall[ks] += __shfl_down(pall[ks], off);
  if ((t & 63) == 0) {
#pragma unroll
    for (int ks = 0; ks < SPLIT2; ++ks) ps[t >> 6][ks] = pall[ks];
  }
  __syncthreads();
  if (t < SPLIT2) csv[t * OUT_F + o] = ps[0][t] + ps[1][t] + ps[2][t] + ps[3][t];
}

// ---- k_out: out[j][o] = d[j]*sum_s P2 + b2[o] (vectorized f32x4) ----
__global__ __launch_bounds__(256) void k_out(const float* __restrict__ P2,
                                             const float* __restrict__ dvec,
                                             const float* __restrict__ b2,
                                             float* __restrict__ out) {
  const int idx = blockIdx.x * 256 + threadIdx.x;  // over N*OUT/4 vec4
  const int j = idx >> 4, o4 = idx & 15;
  const size_t plane4 = (size_t)N_NODES * OUT_F / 4;
  f32x4 s = (f32x4){0.f, 0.f, 0.f, 0.f};
#pragma unroll
  for (int sp = 0; sp < SPLIT2; ++sp) s += ((const f32x4*)P2)[idx + sp * plane4];
  s *= dvec[j];
  s += ((const f32x4*)b2)[o4];
  ((f32x4*)out)[idx] = s;
}

extern "C" void kernel_launch(void* const* d_in, const int* in_sizes, int n_in,
                              void* d_out, int out_size, void* d_ws,
                              size_t ws_size, hipStream_t stream) {
  const float* x   = (const float*)d_in[0];
  const float* adj = (const float*)d_in[1];
  const float* W1  = (const float*)d_in[2];
  const float* b1  = (const float*)d_in[3];
  const float* W2  = (const float*)d_in[4];
  const float* b2  = (const float*)d_in[5];
  float* out = (float*)d_out;
  char* ws = (char*)d_ws;

  size_t off = 0;
  char*  adjq  = ws + off;            off += (size_t)N_NODES * N_NODES;      // 64Mi
  float* dvec  = (float*)(ws + off);  off += (size_t)N_NODES * 4;
  char*  Q1b1  = ws + off;            off += (size_t)IN_F * N_NODES;         // 1Mi
  char*  Q2b1  = ws + off;            off += (size_t)IN_F * N_NODES;         // 1Mi
  float* s1b1  = (float*)(ws + off);  off += 1024;
  float* s2b1  = (float*)(ws + off);  off += 1024;
  float* cs1   = (float*)(ws + off);  off += (size_t)SPLIT1 * IN_F * 4 + 256;
  float* P1    = (float*)(ws + off);  off += (size_t)SPLIT1 * N_NODES * IN_F * 4;
  float* Gf    = (float*)(ws + off);  off += (size_t)OUT_F * N_NODES * 4;    // 2Mi
  char*  Q1b2  = ws + off;            off += (size_t)OUT_F * N_NODES;        // 512Ki
  char*  Q2b2  = ws + off;            off += (size_t)OUT_F * N_NODES;        // 512Ki
  float* s1b2  = (float*)(ws + off);  off += 1024;
  float* s2b2  = (float*)(ws + off);  off += 1024;
  float* cs2   = (float*)(ws + off);  off += (size_t)SPLIT2 * OUT_F * 4 + 256;
  float* P2    = (float*)(ws + off);  // +16Mi, total ~101 MiB

  hipLaunchKernelGGL(k_degcvt, dim3(N_NODES), dim3(256), 0, stream, adj, adjq, dvec);
  hipLaunchKernelGGL(k_bt1q, dim3(IN_F), dim3(256), 0, stream, x, dvec,
                     Q1b1, Q2b1, s1b1, s2b1, cs1);
  // GEMM1: block 128x128, split-K=4 -> grid (64,4), KC=2048
  hipLaunchKernelGGL((k_gemm_i8<2, 2, N_NODES / SPLIT1>),
                     dim3(N_NODES / 128, SPLIT1), dim3(256), 0, stream,
                     adjq, Q1b1, Q2b1, s1b1, s2b1, cs1, P1);
  hipLaunchKernelGGL(k_red_mlp, dim3(N_NODES / 16), dim3(256), 0, stream, P1,
                     dvec, W1, b1, W2, Gf);
  hipLaunchKernelGGL(k_quant2, dim3(OUT_F), dim3(256), 0, stream, Gf,
                     Q1b2, Q2b2, s1b2, s2b2, cs2);
  // GEMM2: block 256x64, split-K=8 -> grid (32,8), KC=1024
  hipLaunchKernelGGL((k_gemm_i8<4, 1, N_NODES / SPLIT2>),
                     dim3(N_NODES / 256, SPLIT2), dim3(256), 0, stream,
                     adjq, Q1b2, Q2b2, s1b2, s2b2, cs2, P2);
  hipLaunchKernelGGL(k_out, dim3((N_NODES * OUT_F / 4) / 256), dim3(256), 0,
                     stream, P2, dvec, b2, out);
}

// Round 5
// 452.575 us; speedup vs baseline: 1.0809x; 1.0143x over previous
//
#include <hip/hip_runtime.h>
#include <hip/hip_bf16.h>

typedef float f32x4 __attribute__((ext_vector_type(4)));
typedef int   i32x4 __attribute__((ext_vector_type(4)));
typedef int   i32x2 __attribute__((ext_vector_type(2)));
typedef __bf16 bf16x8 __attribute__((ext_vector_type(8)));
typedef __bf16 bf16x4 __attribute__((ext_vector_type(4)));

#define N_NODES 8192
#define IN_F    128
#define HID_F   256
#define OUT_F   64
#define SPLIT1  8
#define SPLIT2  16

// async global->LDS DMA, 16B per lane. LDS dst = wave-uniform base + lane*16.
__device__ __forceinline__ void dma16(const void* g, void* l) {
  __builtin_amdgcn_global_load_lds(
      (const __attribute__((address_space(1))) void*)g,
      (__attribute__((address_space(3))) void*)(uint32_t)(uintptr_t)l, 16, 0, 0);
}

// counted vmcnt wait — immediate must be a literal in the instruction text.
template <int K> __device__ __forceinline__ void wait_vmcnt() {
  if constexpr (K == 0)       asm volatile("s_waitcnt vmcnt(0)" ::: "memory");
  else if constexpr (K == 4)  asm volatile("s_waitcnt vmcnt(4)" ::: "memory");
  else if constexpr (K == 5)  asm volatile("s_waitcnt vmcnt(5)" ::: "memory");
  else if constexpr (K == 8)  asm volatile("s_waitcnt vmcnt(8)" ::: "memory");
  else if constexpr (K == 10) asm volatile("s_waitcnt vmcnt(10)" ::: "memory");
  else if constexpr (K == 12) asm volatile("s_waitcnt vmcnt(12)" ::: "memory");
  else if constexpr (K == 15) asm volatile("s_waitcnt vmcnt(15)" ::: "memory");
  else static_assert(K == 0, "unsupported vmcnt literal");
}

// ---- Kernel 1: deg rowsum + fp32->i8 quantize of adj (zero-point 127) ----
// adj in [0,1): q = rint(254*adj - 127) in [-127,127]; A = (q+127)/254 exactly.
__global__ __launch_bounds__(256) void k_degcvt(const float* __restrict__ adj,
                                                char* __restrict__ adjq,
                                                float* __restrict__ d) {
  const int row = blockIdx.x;
  const int t = threadIdx.x;
  const f32x4* p = (const f32x4*)(adj + (size_t)row * N_NODES);
  i32x2* qo = (i32x2*)(adjq + (size_t)row * N_NODES);
  float s = 0.f;
#pragma unroll
  for (int i = 0; i < N_NODES / (256 * 8); ++i) {
    f32x4 a = p[i * 512 + 2 * t];
    f32x4 b = p[i * 512 + 2 * t + 1];
    s += a[0] + a[1] + a[2] + a[3] + b[0] + b[1] + b[2] + b[3];
    int q0 = __float2int_rn(fmaf(a[0], 254.f, -127.f));
    int q1 = __float2int_rn(fmaf(a[1], 254.f, -127.f));
    int q2 = __float2int_rn(fmaf(a[2], 254.f, -127.f));
    int q3 = __float2int_rn(fmaf(a[3], 254.f, -127.f));
    int q4 = __float2int_rn(fmaf(b[0], 254.f, -127.f));
    int q5 = __float2int_rn(fmaf(b[1], 254.f, -127.f));
    int q6 = __float2int_rn(fmaf(b[2], 254.f, -127.f));
    int q7 = __float2int_rn(fmaf(b[3], 254.f, -127.f));
    i32x2 o;
    o[0] = (q0 & 255) | ((q1 & 255) << 8) | ((q2 & 255) << 16) | ((q3 & 255) << 24);
    o[1] = (q4 & 255) | ((q5 & 255) << 8) | ((q6 & 255) << 16) | ((q7 & 255) << 24);
    qo[i * 256 + t] = o;
  }
#pragma unroll
  for (int off = 32; off > 0; off >>= 1) s += __shfl_down(s, off);
  __shared__ float red[4];
  if ((t & 63) == 0) red[t >> 6] = s;
  __syncthreads();
  if (t == 0) d[row] = rsqrtf(red[0] + red[1] + red[2] + red[3] + 1e-8f);
}

// ---- Kernel 2: per-feature-c i8 quantize of B1[c][j] = d[j]*x[j][c] ----
// per-column scale s1 = max|v|/127; csv[ks][c] = s1 * sum_chunk(Qb) so the
// A zero-point term 127*s1*sum(Qb) is exact for the quantized B.
__global__ __launch_bounds__(256) void k_bt1q(const float* __restrict__ x,
                                              const float* __restrict__ d,
                                              char* __restrict__ Q1,
                                              float* __restrict__ s1v,
                                              float* __restrict__ csv) {
  __shared__ float col[N_NODES];  // 32 KB
  __shared__ float redmx[4];
  __shared__ int psI[4][SPLIT1];
  const int c = blockIdx.x, t = threadIdx.x;
  const int w = t >> 6;
  float mx = 0.f;
#pragma unroll
  for (int i = 0; i < 8; ++i) {
    const int j0 = i * 1024 + t * 4;
#pragma unroll
    for (int k = 0; k < 4; ++k) {
      float v = x[(size_t)(j0 + k) * IN_F + c] * d[j0 + k];
      col[j0 + k] = v;
      mx = fmaxf(mx, fabsf(v));
    }
  }
#pragma unroll
  for (int off = 32; off > 0; off >>= 1) mx = fmaxf(mx, __shfl_down(mx, off));
  if ((t & 63) == 0) redmx[t >> 6] = mx;
  __syncthreads();
  mx = fmaxf(fmaxf(redmx[0], redmx[1]), fmaxf(redmx[2], redmx[3]));
  mx = fmaxf(mx, 1e-20f);
  const float s1 = mx * (1.f / 127.f);
  const float r1 = 127.f / mx;
  if (t == 0) s1v[c] = s1;
  int qsum[SPLIT1];  // chunk = j0>>10 = i exactly (KC=1024)
#pragma unroll
  for (int i = 0; i < 8; ++i) {
    const int j0 = i * 1024 + t * 4;
    int w1 = 0, qs = 0;
#pragma unroll
    for (int k = 0; k < 4; ++k) {
      int q1 = __float2int_rn(col[j0 + k] * r1);
      w1 |= (q1 & 255) << (8 * k);
      qs += q1;
    }
    *(int*)(Q1 + (size_t)c * N_NODES + j0) = w1;
    qsum[i] = qs;
  }
#pragma unroll
  for (int i = 0; i < SPLIT1; ++i)
#pragma unroll
    for (int off = 32; off > 0; off >>= 1) qsum[i] += __shfl_down(qsum[i], off);
  if ((t & 63) == 0) {
#pragma unroll
    for (int i = 0; i < SPLIT1; ++i) psI[w][i] = qsum[i];
  }
  __syncthreads();
  if (t < SPLIT1)
    csv[t * IN_F + c] =
        s1 * (float)(psI[0][t] + psI[1][t] + psI[2][t] + psI[3][t]);
}

__device__ inline bf16x8 load_frag(const float* p) {
  f32x4 a = *(const f32x4*)p;
  f32x4 b = *(const f32x4*)(p + 4);
  bf16x8 o = {(__bf16)a[0], (__bf16)a[1], (__bf16)a[2], (__bf16)a[3],
              (__bf16)b[0], (__bf16)b[1], (__bf16)b[2], (__bf16)b[3]};
  return o;
}

// ---- one pipelined K-step of the i8 DMA-staged GEMM (single B plane) ----
// 4-deep circular LDS pipeline, counted vmcnt. K-step = 64 i8 = 64 B/row.
template <int WGM, int WGN, int KC, int KWAIT>
__device__ __forceinline__ void g_iter(char* sm, int it, int w,
                                       const char* (&a_src)[WGM],
                                       const char* (&b_src)[WGN],
                                       const int (&offA)[4],
                                       const int (&offB)[4],
                                       i32x4 (&acc)[4][4]) {
  constexpr int BM = WGM * 64, BN = WGN * 64;
  constexpr int ABYTES = BM * 64;
  constexpr int STAGE = (BM + BN) * 64;
  constexpr int NIT = KC / 64;

  if (it + 3 < NIT) {  // issue stage it+3 into buf[(it+3)&3]
    char* nb = sm + ((it + 3) & 3) * STAGE;
#pragma unroll
    for (int kk = 0; kk < WGM; ++kk) {
      dma16(a_src[kk], nb + kk * 4096 + (w << 10));
      a_src[kk] += 64;
    }
#pragma unroll
    for (int kk = 0; kk < WGN; ++kk) {
      dma16(b_src[kk], nb + ABYTES + kk * 4096 + (w << 10));
      b_src[kk] += 64;
    }
  }
  __builtin_amdgcn_sched_barrier(0);
  wait_vmcnt<KWAIT>();                       // stage it complete (this wave)
  asm volatile("s_barrier" ::: "memory");    // stage it complete (all waves)
  __builtin_amdgcn_sched_barrier(0);

  const char* cb = sm + (it & 3) * STAGE;
  i32x4 af[4], bf[4];
#pragma unroll
  for (int tm = 0; tm < 4; ++tm) af[tm] = *(const i32x4*)(cb + offA[tm]);
#pragma unroll
  for (int ct = 0; ct < 4; ++ct) bf[ct] = *(const i32x4*)(cb + offB[ct]);
#pragma unroll
  for (int tm = 0; tm < 4; ++tm)
#pragma unroll
    for (int ct = 0; ct < 4; ++ct)
      acc[tm][ct] = __builtin_amdgcn_mfma_i32_16x16x64_i8(af[tm], bf[ct],
                                                          acc[tm][ct], 0, 0, 0);
  __builtin_amdgcn_sched_barrier(0);
  asm volatile("s_waitcnt lgkmcnt(0)" ::: "memory");
  asm volatile("s_barrier" ::: "memory");
}

// ---- i8 DMA-staged MFMA GEMM partials -> bf16 P ----
// P = (s1[c]*Qa@Qb + 127*csq[ks][c]) / 254, csq = s1*sum(Qb) per chunk.
template <int WGM, int WGN, int KC>
__global__ __launch_bounds__(256, 2) void k_gemm_i8(
    const char* __restrict__ A, const char* __restrict__ B,
    const float* __restrict__ s1v, const float* __restrict__ csq,
    __bf16* __restrict__ P) {
  constexpr int BM = WGM * 64, BN = WGN * 64;
  constexpr int ANI = WGM, BNI = WGN;
  constexpr int ABYTES = BM * 64;
  constexpr int STAGE = (BM + BN) * 64;
  constexpr int NIT = KC / 64;
  constexpr int L = ANI + BNI;  // vm loads/thread/stage
  static_assert(NIT > 3, "pipeline needs >3 K-steps");

  __shared__ __align__(16) char sm[4 * STAGE];

  const int t = threadIdx.x;
  const int w = t >> 6, lane = t & 63;
  const int r = lane & 15, q = lane >> 4;
  const int wm = (WGN == 1) ? w : (w >> 1);
  const int wn = (WGN == 1) ? 0 : (w & 1);
  const int m0 = blockIdx.x * BM;
  const int ks = blockIdx.y;
  const int k0 = ks * KC;

  // staging sources: row n_ = t>>2, 16B slot csw (chunk-swizzled in 16B units)
  const int n_ = t >> 2;
  const int csw = (t & 3) ^ ((t >> 3) & 3);
  const char* a_src[ANI];
  const char* b_src[BNI];
#pragma unroll
  for (int kk = 0; kk < ANI; ++kk)
    a_src[kk] = A + (size_t)(m0 + n_ + 64 * kk) * N_NODES + k0 + csw * 16;
#pragma unroll
  for (int kk = 0; kk < BNI; ++kk)
    b_src[kk] = B + (size_t)(n_ + 64 * kk) * N_NODES + k0 + csw * 16;

  // fragment LDS byte offsets: row*64 + (q^((row>>1)&3))*16
  int offA[4], offB[4];
#pragma unroll
  for (int tm = 0; tm < 4; ++tm) {
    const int row = wm * 64 + tm * 16 + r;
    offA[tm] = row * 64 + ((q ^ ((row >> 1) & 3)) << 4);
  }
#pragma unroll
  for (int ct = 0; ct < 4; ++ct) {
    const int row = wn * 64 + ct * 16 + r;
    offB[ct] = ABYTES + row * 64 + ((q ^ ((row >> 1) & 3)) << 4);
  }

  i32x4 acc[4][4];
#pragma unroll
  for (int tm = 0; tm < 4; ++tm)
#pragma unroll
    for (int ct = 0; ct < 4; ++ct) acc[tm][ct] = (i32x4){0, 0, 0, 0};

  // prologue: fill stages 0..2
#pragma unroll
  for (int s = 0; s < 3; ++s) {
    char* sb = sm + s * STAGE;
#pragma unroll
    for (int kk = 0; kk < ANI; ++kk) {
      dma16(a_src[kk], sb + kk * 4096 + (w << 10));
      a_src[kk] += 64;
    }
#pragma unroll
    for (int kk = 0; kk < BNI; ++kk) {
      dma16(b_src[kk], sb + ABYTES + kk * 4096 + (w << 10));
      b_src[kk] += 64;
    }
  }

  for (int it = 0; it < NIT - 3; ++it)
    g_iter<WGM, WGN, KC, 3 * L>(sm, it, w, a_src, b_src, offA, offB, acc);
  g_iter<WGM, WGN, KC, 2 * L>(sm, NIT - 3, w, a_src, b_src, offA, offB, acc);
  g_iter<WGM, WGN, KC, L>(sm, NIT - 2, w, a_src, b_src, offA, offB, acc);
  g_iter<WGM, WGN, KC, 0>(sm, NIT - 1, w, a_src, b_src, offA, offB, acc);

  // epilogue: dequant -> bf16. C/D layout col=lane&15, row=q*4+reg
  __bf16* pout =
      P + ((size_t)ks * N_NODES + m0 + wm * 64 + q * 4) * BN + wn * 64 + r;
#pragma unroll
  for (int ct = 0; ct < 4; ++ct) {
    const int col = wn * 64 + ct * 16 + r;
    const float s1c = s1v[col];
    const float corr = 127.f * csq[ks * BN + col];
#pragma unroll
    for (int tm = 0; tm < 4; ++tm)
#pragma unroll
      for (int i = 0; i < 4; ++i)
        pout[(size_t)(tm * 16 + i) * BN + ct * 16] =
            (__bf16)((s1c * (float)acc[tm][ct][i] + corr) * (1.f / 254.f));
  }
}

// ---- reduce P1 (bf16, SPLIT1 planes) + MLP + write Gf[o][j] = d[j]*g ----
__global__ __launch_bounds__(256) void k_red_mlp(const __bf16* __restrict__ P1,
                                                 const float* __restrict__ dvec,
                                                 const float* __restrict__ W1,
                                                 const float* __restrict__ b1,
                                                 const float* __restrict__ W2,
                                                 float* __restrict__ Gf) {
  __shared__ __align__(16) float y[16][IN_F + 4];
  __shared__ __align__(16) __bf16 h[16][HID_F + 8];
  __shared__ __align__(16) float gl[OUT_F][20];
  __shared__ float dl[16];
  const int t = threadIdx.x;
  const int lane = t & 63;
  const int w = t >> 6;
  const int r = lane & 15, q = lane >> 4;
  const int j0 = blockIdx.x * 16;

  if (t < 16) dl[t] = dvec[j0 + t];
  const size_t planeB4 = (size_t)N_NODES * IN_F / 4;  // bf16x4 units
  for (int e = t; e < 16 * IN_F / 4; e += 256) {
    const int jj = e >> 5, c4 = e & 31;
    const size_t base = (size_t)(j0 + jj) * (IN_F / 4) + c4;
    f32x4 v = (f32x4){0.f, 0.f, 0.f, 0.f};
#pragma unroll
    for (int s = 0; s < SPLIT1; ++s) {
      bf16x4 b = ((const bf16x4*)P1)[base + s * planeB4];
      v[0] += (float)b[0]; v[1] += (float)b[1];
      v[2] += (float)b[2]; v[3] += (float)b[3];
    }
    const float dj = dvec[j0 + jj];
    v *= dj;
    *(f32x4*)&y[jj][c4 * 4] = v;
  }
  __syncthreads();

  // h tile: wave w -> hid cols [w*64, w*64+64)
  f32x4 hacc[4];
#pragma unroll
  for (int tt = 0; tt < 4; ++tt) hacc[tt] = (f32x4){0.f, 0.f, 0.f, 0.f};
#pragma unroll
  for (int kt = 0; kt < 4; ++kt) {
    bf16x8 afr = load_frag((const float*)&y[r][kt * 32 + q * 8]);
#pragma unroll
    for (int tt = 0; tt < 4; ++tt) {
      const int col = w * 64 + tt * 16 + r;
      bf16x8 bfr = load_frag(W1 + (size_t)col * IN_F + kt * 32 + q * 8);
      hacc[tt] = __builtin_amdgcn_mfma_f32_16x16x32_bf16(afr, bfr, hacc[tt], 0, 0, 0);
    }
  }
#pragma unroll
  for (int tt = 0; tt < 4; ++tt) {
    const int col = w * 64 + tt * 16 + r;
    const float bias = b1[col];
#pragma unroll
    for (int i = 0; i < 4; ++i)
      h[q * 4 + i][col] = (__bf16)fmaxf(hacc[tt][i] + bias, 0.f);
  }
  __syncthreads();

  // g tile: wave w -> out cols [w*16, w*16+16), K=256
  f32x4 gacc = (f32x4){0.f, 0.f, 0.f, 0.f};
  const int o = w * 16 + r;
#pragma unroll
  for (int kt = 0; kt < 8; ++kt) {
    bf16x8 afr = *(const bf16x8*)&h[r][kt * 32 + q * 8];
    bf16x8 bfr = load_frag(W2 + (size_t)o * HID_F + kt * 32 + q * 8);
    gacc = __builtin_amdgcn_mfma_f32_16x16x32_bf16(afr, bfr, gacc, 0, 0, 0);
  }
#pragma unroll
  for (int i = 0; i < 4; ++i) gl[o][q * 4 + i] = gacc[i];
  __syncthreads();

  const int oo = t >> 2, r0 = (t & 3) * 4;
  f32x4 ov;
#pragma unroll
  for (int rr = 0; rr < 4; ++rr) ov[rr] = gl[oo][r0 + rr] * dl[r0 + rr];
  *(f32x4*)(Gf + (size_t)oo * N_NODES + j0 + r0) = ov;
}

// ---- per-o i8 quantize of B2[o][j] = Gf[o][j] + quantized chunk colsums ----
// KC=512: chunk = j0>>9 = 2*i + (t>=128); waves 0,1 -> even, 2,3 -> odd.
__global__ __launch_bounds__(256) void k_quant2(const float* __restrict__ G,
                                                char* __restrict__ Q1,
                                                float* __restrict__ s1v,
                                                float* __restrict__ csv) {
  __shared__ float redmx[4];
  __shared__ int psI[4][8];
  const int o = blockIdx.x, t = threadIdx.x;
  const int w = t >> 6;
  const float* row = G + (size_t)o * N_NODES;
  f32x4 vv[8];
  float mx = 0.f;
#pragma unroll
  for (int i = 0; i < 8; ++i) {
    vv[i] = ((const f32x4*)row)[i * 256 + t];
    mx = fmaxf(mx, fmaxf(fmaxf(fabsf(vv[i][0]), fabsf(vv[i][1])),
                         fmaxf(fabsf(vv[i][2]), fabsf(vv[i][3]))));
  }
#pragma unroll
  for (int off = 32; off > 0; off >>= 1) mx = fmaxf(mx, __shfl_down(mx, off));
  if ((t & 63) == 0) redmx[t >> 6] = mx;
  __syncthreads();
  mx = fmaxf(fmaxf(redmx[0], redmx[1]), fmaxf(redmx[2], redmx[3]));
  mx = fmaxf(mx, 1e-20f);
  const float s1 = mx * (1.f / 127.f);
  const float r1 = 127.f / mx;
  if (t == 0) s1v[o] = s1;
  int qc[8];
#pragma unroll
  for (int i = 0; i < 8; ++i) {
    const int j0 = i * 1024 + t * 4;
    int w1 = 0, qs = 0;
#pragma unroll
    for (int k = 0; k < 4; ++k) {
      int q1 = __float2int_rn(vv[i][k] * r1);
      w1 |= (q1 & 255) << (8 * k);
      qs += q1;
    }
    *(int*)(Q1 + (size_t)o * N_NODES + j0) = w1;
    qc[i] = qs;
  }
#pragma unroll
  for (int i = 0; i < 8; ++i)
#pragma unroll
    for (int off = 32; off > 0; off >>= 1) qc[i] += __shfl_down(qc[i], off);
  if ((t & 63) == 0) {
#pragma unroll
    for (int i = 0; i < 8; ++i) psI[w][i] = qc[i];
  }
  __syncthreads();
  if (t < SPLIT2) {
    const int i = t >> 1;
    const int sum = (t & 1) ? psI[2][i] + psI[3][i] : psI[0][i] + psI[1][i];
    csv[t * OUT_F + o] = s1 * (float)sum;
  }
}

// ---- k_out: out[j][o] = d[j]*sum_s P2 + b2[o] ----
__global__ __launch_bounds__(256) void k_out(const __bf16* __restrict__ P2,
                                             const float* __restrict__ dvec,
                                             const float* __restrict__ b2,
                                             float* __restrict__ out) {
  const int idx = blockIdx.x * 256 + threadIdx.x;  // over N*OUT/4 vec4
  const int j = idx >> 4, o4 = idx & 15;
  const size_t planeB4 = (size_t)N_NODES * OUT_F / 4;
  f32x4 s = (f32x4){0.f, 0.f, 0.f, 0.f};
#pragma unroll
  for (int sp = 0; sp < SPLIT2; ++sp) {
    bf16x4 b = ((const bf16x4*)P2)[idx + sp * planeB4];
    s[0] += (float)b[0]; s[1] += (float)b[1];
    s[2] += (float)b[2]; s[3] += (float)b[3];
  }
  s *= dvec[j];
  s += ((const f32x4*)b2)[o4];
  ((f32x4*)out)[idx] = s;
}

extern "C" void kernel_launch(void* const* d_in, const int* in_sizes, int n_in,
                              void* d_out, int out_size, void* d_ws,
                              size_t ws_size, hipStream_t stream) {
  const float* x   = (const float*)d_in[0];
  const float* adj = (const float*)d_in[1];
  const float* W1  = (const float*)d_in[2];
  const float* b1  = (const float*)d_in[3];
  const float* W2  = (const float*)d_in[4];
  const float* b2  = (const float*)d_in[5];
  float* out = (float*)d_out;
  char* ws = (char*)d_ws;

  size_t off = 0;
  char*  adjq  = ws + off;            off += (size_t)N_NODES * N_NODES;      // 64Mi
  float* dvec  = (float*)(ws + off);  off += (size_t)N_NODES * 4;
  char*  Q1b1  = ws + off;            off += (size_t)IN_F * N_NODES;         // 1Mi
  float* s1b1  = (float*)(ws + off);  off += 1024;
  float* cs1   = (float*)(ws + off);  off += (size_t)SPLIT1 * IN_F * 4 + 256;
  __bf16* P1   = (__bf16*)(ws + off); off += (size_t)SPLIT1 * N_NODES * IN_F * 2;  // 16Mi
  float* Gf    = (float*)(ws + off);  off += (size_t)OUT_F * N_NODES * 4;    // 2Mi
  char*  Q1b2  = ws + off;            off += (size_t)OUT_F * N_NODES;        // 512Ki
  float* s1b2  = (float*)(ws + off);  off += 1024;
  float* cs2   = (float*)(ws + off);  off += (size_t)SPLIT2 * OUT_F * 4 + 256;
  __bf16* P2   = (__bf16*)(ws + off); // 16Mi, total ~100 MiB

  hipLaunchKernelGGL(k_degcvt, dim3(N_NODES), dim3(256), 0, stream, adj, adjq, dvec);
  hipLaunchKernelGGL(k_bt1q, dim3(IN_F), dim3(256), 0, stream, x, dvec,
                     Q1b1, s1b1, cs1);
  // GEMM1: block 128x128, split-K=8 -> grid (64,8), KC=1024, 2 blk/CU
  hipLaunchKernelGGL((k_gemm_i8<2, 2, N_NODES / SPLIT1>),
                     dim3(N_NODES / 128, SPLIT1), dim3(256), 0, stream,
                     adjq, Q1b1, s1b1, cs1, P1);
  hipLaunchKernelGGL(k_red_mlp, dim3(N_NODES / 16), dim3(256), 0, stream, P1,
                     dvec, W1, b1, W2, Gf);
  hipLaunchKernelGGL(k_quant2, dim3(OUT_F), dim3(256), 0, stream, Gf,
                     Q1b2, s1b2, cs2);
  // GEMM2: block 256x64, split-K=16 -> grid (32,16), KC=512, 2 blk/CU
  hipLaunchKernelGGL((k_gemm_i8<4, 1, N_NODES / SPLIT2>),
                     dim3(N_NODES / 256, SPLIT2), dim3(256), 0, stream,
                     adjq, Q1b2, s1b2, cs2, P2);
  hipLaunchKernelGGL(k_out, dim3((N_NODES * OUT_F / 4) / 256), dim3(256), 0,
                     stream, P2, dvec, b2, out);
}